// Round 1
// baseline (1158.003 us; speedup 1.0000x reference)
//
#include <hip/hip_runtime.h>
#include <hip/hip_bf16.h>

typedef float  v4f __attribute__((ext_vector_type(4)));
typedef short  v8s __attribute__((ext_vector_type(8)));
typedef int    v4i __attribute__((ext_vector_type(4)));

#define DEV static __device__ __forceinline__

DEV float bf2f(unsigned short u) {
    union { unsigned int i; float f; } x; x.i = ((unsigned int)u) << 16; return x.f;
}
DEV unsigned short f2bf(float f) {
    union { float f; unsigned int i; } x; x.f = f;
    unsigned int r = x.i + 0x7fff + ((x.i >> 16) & 1);
    return (unsigned short)(r >> 16);
}
DEV float sigm(float x) { return 1.f / (1.f + __expf(-x)); }

// ---------------------------------------------------------------------------
// uber_init: all fp32->bf16 weight conversions + Wz concat + emb gather +
// mean_enc + bz. Segment if-ladder over flat index. All coalesced.
// ---------------------------------------------------------------------------
__global__ __launch_bounds__(256) void uber_init(
    const float* __restrict__ Wih, const float* __restrict__ Whh,
    const float* __restrict__ bih, const float* __restrict__ bhh,
    const float* __restrict__ WoutF, const float* __restrict__ WeattF,
    const float* __restrict__ WdattF, const float* __restrict__ Wh0F,
    const float* __restrict__ Wc0F, const float* __restrict__ enc,
    const int* __restrict__ caps, const float* __restrict__ embed,
    unsigned short* __restrict__ Wz, unsigned short* __restrict__ Woutb,
    unsigned short* __restrict__ Weattb, unsigned short* __restrict__ Wdattb,
    unsigned short* __restrict__ Wh0b, unsigned short* __restrict__ Wc0b,
    unsigned short* __restrict__ encb, unsigned short* __restrict__ embb,
    unsigned short* __restrict__ meanb, float* __restrict__ bz)
{
    int i = blockIdx.x * 256 + threadIdx.x;
    if (i < 11534336) {                       // Wz = [W_ih | W_hh] rows of 2816
        int n = i / 2816, k = i - n * 2816;
        float v = (k < 1792) ? Wih[n * 1792 + k] : Whh[n * 1024 + (k - 1792)];
        Wz[i] = f2bf(v);
    } else if (i < 21774336) {                // W_out
        int j = i - 11534336; Woutb[j] = f2bf(WoutF[j]);
    } else if (i < 22429696) {                // W_eatt
        int j = i - 21774336; Weattb[j] = f2bf(WeattF[j]);
    } else if (i < 22953984) {                // W_datt
        int j = i - 22429696; Wdattb[j] = f2bf(WdattF[j]);
    } else if (i < 24264704) {                // W_h0
        int j = i - 22953984; Wh0b[j] = f2bf(Wh0F[j]);
    } else if (i < 25575424) {                // W_c0
        int j = i - 24264704; Wc0b[j] = f2bf(Wc0F[j]);
    } else if (i < 29589504) {                // encoder_out
        int j = i - 25575424; encb[j] = f2bf(enc[j]);
    } else if (i < 30375936) {                // emb gather (t < 24 only)
        int j = i - 29589504;
        int b = j / 12288, r = j - b * 12288, t = r / 512, e = r - t * 512;
        embb[j] = f2bf(embed[caps[b * 25 + t] * 512 + e]);
    } else if (i < 30457856) {                // mean over P=49
        int j = i - 30375936;
        int b = j / 1280, c = j - b * 1280;
        float s = 0.f;
        for (int p = 0; p < 49; ++p) s += enc[(b * 49 + p) * 1280 + c];
        meanb[j] = f2bf(s * (1.f / 49.f));
    } else if (i < 30461952) {                // bz = b_ih + b_hh
        int j = i - 30457856; bz[j] = bih[j] + bhh[j];
    }
}

// ---------------------------------------------------------------------------
// gemm64_bn16: C[64,N] = A[64,K](bf16) @ B[N,K](bf16)^T + bias. BN=16/block.
// 4 waves: wave w -> m-quarter [16w,16w+16). BK=256. K % 256 == 0.
// OUT_BF16: 1 -> bf16 store, 0 -> fp32 store.
// ---------------------------------------------------------------------------
template <int OUT_BF16>
__global__ __launch_bounds__(256) void gemm64_bn16(
    const unsigned short* __restrict__ Ag, int lda,
    const unsigned short* __restrict__ Bg, int K,
    const float* __restrict__ bias, void* __restrict__ Cg, int ldc)
{
    __shared__ unsigned short lA[64 * 264];
    __shared__ unsigned short lB[16 * 264];
    const int tid = threadIdx.x, lane = tid & 63, w = tid >> 6;
    const int nb = blockIdx.x * 16;
    v4f acc = {0.f, 0.f, 0.f, 0.f};
    for (int kt = 0; kt < K; kt += 256) {
#pragma unroll
        for (int i = 0; i < 8; ++i) {
            int gid = i * 256 + tid, r = gid >> 5, c = (gid & 31) * 8;
            *(v4i*)&lA[r * 264 + c] = *(const v4i*)&Ag[r * lda + kt + c];
        }
#pragma unroll
        for (int i = 0; i < 2; ++i) {
            int gid = i * 256 + tid, r = gid >> 5, c = (gid & 31) * 8;
            *(v4i*)&lB[r * 264 + c] = *(const v4i*)&Bg[(nb + r) * K + kt + c];
        }
        __syncthreads();
#pragma unroll
        for (int ks = 0; ks < 8; ++ks) {
            v8s a = *(const v8s*)&lA[(w * 16 + (lane & 15)) * 264 + ks * 32 + (lane >> 4) * 8];
            v8s b = *(const v8s*)&lB[(lane & 15) * 264 + ks * 32 + (lane >> 4) * 8];
            acc = __builtin_amdgcn_mfma_f32_16x16x32_bf16(a, b, acc, 0, 0, 0);
        }
        __syncthreads();
    }
    const int n = nb + (lane & 15);
    const float bs = bias[n];
#pragma unroll
    for (int r = 0; r < 4; ++r) {
        int m = w * 16 + (lane >> 4) * 4 + r;
        float v = acc[r] + bs;
        if (OUT_BF16) ((unsigned short*)Cg)[m * ldc + n] = f2bf(v);
        else          ((float*)Cg)[m * ldc + n] = v;
    }
}

// ---------------------------------------------------------------------------
// gemm_att1: att1[3136,512](bf16) = enc_b[3136,1280] @ W_eatt[512,1280]^T + b
// Tile 64x64, BK=128. grid = (N/64=8, M/64=49)
// ---------------------------------------------------------------------------
__global__ __launch_bounds__(256) void gemm_att1_k(
    const unsigned short* __restrict__ Aenc, const unsigned short* __restrict__ Bw,
    const float* __restrict__ bias, unsigned short* __restrict__ Cout)
{
    __shared__ unsigned short lA[64 * 136];
    __shared__ unsigned short lB[64 * 136];
    const int tid = threadIdx.x, lane = tid & 63, w = tid >> 6;
    const int mb = blockIdx.y * 64, nb = blockIdx.x * 64;
    v4f acc[4];
#pragma unroll
    for (int f = 0; f < 4; ++f) acc[f] = (v4f){0.f, 0.f, 0.f, 0.f};
    for (int kt = 0; kt < 1280; kt += 128) {
#pragma unroll
        for (int i = 0; i < 4; ++i) {
            int gid = i * 256 + tid, r = gid >> 4, c = (gid & 15) * 8;
            *(v4i*)&lA[r * 136 + c] = *(const v4i*)&Aenc[(mb + r) * 1280 + kt + c];
            *(v4i*)&lB[r * 136 + c] = *(const v4i*)&Bw[(nb + r) * 1280 + kt + c];
        }
        __syncthreads();
#pragma unroll
        for (int ks = 0; ks < 4; ++ks) {
            v8s a = *(const v8s*)&lA[(w * 16 + (lane & 15)) * 136 + ks * 32 + (lane >> 4) * 8];
#pragma unroll
            for (int f = 0; f < 4; ++f) {
                v8s b = *(const v8s*)&lB[(f * 16 + (lane & 15)) * 136 + ks * 32 + (lane >> 4) * 8];
                acc[f] = __builtin_amdgcn_mfma_f32_16x16x32_bf16(a, b, acc[f], 0, 0, 0);
            }
        }
        __syncthreads();
    }
#pragma unroll
    for (int f = 0; f < 4; ++f) {
        int n = nb + f * 16 + (lane & 15);
        float bs = bias[n];
#pragma unroll
        for (int r = 0; r < 4; ++r) {
            int m = mb + w * 16 + (lane >> 4) * 4 + r;
            Cout[m * 512 + n] = f2bf(acc[f][r] + bs);
        }
    }
}

// ---------------------------------------------------------------------------
// attn_ctx: per-b block. e = relu(att1+att2)@W_fatt + b_fatt, softmax over P,
// ctx = alpha @ enc; writes z[:,512:1792]=bf16(ctx), z[:,0:512]=emb_t.
// ---------------------------------------------------------------------------
__global__ __launch_bounds__(256) void attn_ctx_k(
    const float* __restrict__ att2, const unsigned short* __restrict__ att1b,
    const float* __restrict__ Wfatt, const float* __restrict__ bfatt,
    const unsigned short* __restrict__ encb, const unsigned short* __restrict__ embb,
    unsigned short* __restrict__ z, int tstep)
{
    __shared__ float a2[512];
    __shared__ float wf[512];
    __shared__ float es[64];
    __shared__ float alpha[64];
    const int tid = threadIdx.x, lane = tid & 63, w = tid >> 6;
    const int b = blockIdx.x;
    a2[tid]       = att2[b * 512 + tid];
    a2[tid + 256] = att2[b * 512 + tid + 256];
    wf[tid]       = Wfatt[tid];
    wf[tid + 256] = Wfatt[tid + 256];
    __syncthreads();
    for (int p = w; p < 49; p += 4) {
        float s = 0.f;
#pragma unroll
        for (int i = 0; i < 8; ++i) {
            int a = lane + i * 64;
            float v = bf2f(att1b[(b * 49 + p) * 512 + a]) + a2[a];
            s += fmaxf(v, 0.f) * wf[a];
        }
#pragma unroll
        for (int off = 32; off > 0; off >>= 1) s += __shfl_xor(s, off);
        if (lane == 0) es[p] = s + bfatt[0];
    }
    __syncthreads();
    if (w == 0) {
        float v = (lane < 49) ? es[lane] : -1e30f;
        float m = v;
#pragma unroll
        for (int off = 32; off > 0; off >>= 1) m = fmaxf(m, __shfl_xor(m, off));
        float e = (lane < 49) ? __expf(v - m) : 0.f;
        float s = e;
#pragma unroll
        for (int off = 32; off > 0; off >>= 1) s += __shfl_xor(s, off);
        if (lane < 49) alpha[lane] = e / s;
    }
    __syncthreads();
    for (int j = tid; j < 1280; j += 256) {
        float s = 0.f;
#pragma unroll
        for (int p = 0; p < 49; ++p)
            s += alpha[p] * bf2f(encb[(b * 49 + p) * 1280 + j]);
        z[b * 2816 + 512 + j] = f2bf(s);
    }
    for (int j = tid; j < 512; j += 256)
        z[b * 2816 + j] = embb[(b * 24 + tstep) * 512 + j];
}

// ---------------------------------------------------------------------------
// gates_lstm: gates[64, 4096] = z[64,2816] @ Wz[4096,2816]^T + bz, fused LSTM.
// Block = 4 h-cols x 4 gates (16 gathered B rows) x all 64 b. grid = 256.
// Epilogue: LDS transpose -> per-thread (b, h): c/h update; h_new (bf16) ->
// z h-slot and Hall[t].
// ---------------------------------------------------------------------------
__global__ __launch_bounds__(256) void gates_lstm_k(
    const unsigned short* __restrict__ z, const unsigned short* __restrict__ Wz,
    const float* __restrict__ bz, float* __restrict__ cst,
    unsigned short* __restrict__ zh, unsigned short* __restrict__ HallT)
{
    __shared__ unsigned short lA[64 * 264];
    __shared__ unsigned short lB[16 * 264];
    __shared__ float gbuf[64 * 20];
    const int tid = threadIdx.x, lane = tid & 63, w = tid >> 6;
    const int hb = blockIdx.x * 4;
    v4f acc = {0.f, 0.f, 0.f, 0.f};
    for (int kt = 0; kt < 2816; kt += 256) {
#pragma unroll
        for (int i = 0; i < 8; ++i) {
            int gid = i * 256 + tid, r = gid >> 5, c = (gid & 31) * 8;
            *(v4i*)&lA[r * 264 + c] = *(const v4i*)&z[r * 2816 + kt + c];
        }
#pragma unroll
        for (int i = 0; i < 2; ++i) {
            int gid = i * 256 + tid, r = gid >> 5, c = (gid & 31) * 8;
            int gate = r & 3, hco = r >> 2;
            int grow = gate * 1024 + hb + hco;
            *(v4i*)&lB[r * 264 + c] = *(const v4i*)&Wz[grow * 2816 + kt + c];
        }
        __syncthreads();
#pragma unroll
        for (int ks = 0; ks < 8; ++ks) {
            v8s a = *(const v8s*)&lA[(w * 16 + (lane & 15)) * 264 + ks * 32 + (lane >> 4) * 8];
            v8s b = *(const v8s*)&lB[(lane & 15) * 264 + ks * 32 + (lane >> 4) * 8];
            acc = __builtin_amdgcn_mfma_f32_16x16x32_bf16(a, b, acc, 0, 0, 0);
        }
        __syncthreads();
    }
#pragma unroll
    for (int r = 0; r < 4; ++r) {
        int m = w * 16 + (lane >> 4) * 4 + r;   // = b
        int n = lane & 15;                      // = hco*4 + gate
        gbuf[m * 20 + n] = acc[r];
    }
    __syncthreads();
    const int b = tid >> 2, hco = tid & 3, hidx = hb + hco;
    float gi = gbuf[b * 20 + hco * 4 + 0] + bz[hidx];
    float gf = gbuf[b * 20 + hco * 4 + 1] + bz[1024 + hidx];
    float gg = gbuf[b * 20 + hco * 4 + 2] + bz[2048 + hidx];
    float go = gbuf[b * 20 + hco * 4 + 3] + bz[3072 + hidx];
    float cn = sigm(gf) * cst[b * 1024 + hidx] + sigm(gi) * tanhf(gg);
    float hn = sigm(go) * tanhf(cn);
    cst[b * 1024 + hidx] = cn;
    unsigned short hb16 = f2bf(hn);
    zh[b * 2816 + hidx] = hb16;
    HallT[b * 1024 + hidx] = hb16;
}

// ---------------------------------------------------------------------------
// preds: out[b,t,v] = Hall[1536,1024] @ W_out[10000,1024]^T + b_out
// Tile 128x128, BK=64, 4 waves each 32m x 128n. grid = (79, 12).
// ---------------------------------------------------------------------------
__global__ __launch_bounds__(256) void preds_k(
    const unsigned short* __restrict__ Hall, const unsigned short* __restrict__ Wout,
    const float* __restrict__ bout, float* __restrict__ out)
{
    __shared__ unsigned short lA[128 * 72];
    __shared__ unsigned short lB[128 * 72];
    const int tid = threadIdx.x, lane = tid & 63, w = tid >> 6;
    const int mb = blockIdx.y * 128, nb = blockIdx.x * 128;
    v4f acc[2][8];
#pragma unroll
    for (int i = 0; i < 2; ++i)
#pragma unroll
        for (int f = 0; f < 8; ++f) acc[i][f] = (v4f){0.f, 0.f, 0.f, 0.f};
    for (int kt = 0; kt < 1024; kt += 64) {
#pragma unroll
        for (int i = 0; i < 4; ++i) {
            int gid = i * 256 + tid, r = gid >> 3, c = (gid & 7) * 8;
            *(v4i*)&lA[r * 72 + c] = *(const v4i*)&Hall[(mb + r) * 1024 + kt + c];
            int n = nb + r; if (n > 9999) n = 9999;
            *(v4i*)&lB[r * 72 + c] = *(const v4i*)&Wout[n * 1024 + kt + c];
        }
        __syncthreads();
#pragma unroll
        for (int ks = 0; ks < 2; ++ks) {
            int ko = ks * 32 + (lane >> 4) * 8;
            v8s a0 = *(const v8s*)&lA[(w * 32 + (lane & 15)) * 72 + ko];
            v8s a1 = *(const v8s*)&lA[(w * 32 + 16 + (lane & 15)) * 72 + ko];
#pragma unroll
            for (int f = 0; f < 8; ++f) {
                v8s b = *(const v8s*)&lB[(f * 16 + (lane & 15)) * 72 + ko];
                acc[0][f] = __builtin_amdgcn_mfma_f32_16x16x32_bf16(a0, b, acc[0][f], 0, 0, 0);
                acc[1][f] = __builtin_amdgcn_mfma_f32_16x16x32_bf16(a1, b, acc[1][f], 0, 0, 0);
            }
        }
        __syncthreads();
    }
#pragma unroll
    for (int f = 0; f < 8; ++f) {
        int n = nb + f * 16 + (lane & 15);
        if (n < 10000) {
            float bs = bout[n];
#pragma unroll
            for (int i = 0; i < 2; ++i)
#pragma unroll
                for (int r = 0; r < 4; ++r) {
                    int m = mb + w * 32 + i * 16 + (lane >> 4) * 4 + r;
                    int tt = m >> 6, bb = m & 63;
                    out[(bb * 24 + tt) * 10000 + n] = acc[i][f][r] + bs;
                }
        }
    }
}

// ---------------------------------------------------------------------------
extern "C" void kernel_launch(void* const* d_in, const int* in_sizes, int n_in,
                              void* d_out, int out_size, void* d_ws, size_t ws_size,
                              hipStream_t stream)
{
    const float* enc   = (const float*)d_in[0];
    const int*   caps  = (const int*)d_in[1];
    const float* embed = (const float*)d_in[2];
    const float* Weatt = (const float*)d_in[3];
    const float* beatt = (const float*)d_in[4];
    const float* Wdatt = (const float*)d_in[5];
    const float* bdatt = (const float*)d_in[6];
    const float* Wfatt = (const float*)d_in[7];
    const float* bfatt = (const float*)d_in[8];
    const float* Wih   = (const float*)d_in[9];
    const float* bih   = (const float*)d_in[10];
    const float* Whh   = (const float*)d_in[11];
    const float* bhh   = (const float*)d_in[12];
    const float* Wh0   = (const float*)d_in[13];
    const float* bh0   = (const float*)d_in[14];
    const float* Wc0   = (const float*)d_in[15];
    const float* bc0   = (const float*)d_in[16];
    const float* WoutF = (const float*)d_in[17];
    const float* bout  = (const float*)d_in[18];
    float* out = (float*)d_out;

    char* ws = (char*)d_ws;
    size_t off = 0;
    auto carve = [&](size_t bytes) -> void* {
        void* p = ws + off; off += (bytes + 255) & ~(size_t)255; return p;
    };
    unsigned short* Wzb    = (unsigned short*)carve(11534336ull * 2);
    unsigned short* Woutb  = (unsigned short*)carve(10240000ull * 2);
    unsigned short* Weattb = (unsigned short*)carve(655360ull * 2);
    unsigned short* Wdattb = (unsigned short*)carve(524288ull * 2);
    unsigned short* Wh0b   = (unsigned short*)carve(1310720ull * 2);
    unsigned short* Wc0b   = (unsigned short*)carve(1310720ull * 2);
    unsigned short* encb   = (unsigned short*)carve(4014080ull * 2);
    unsigned short* embb   = (unsigned short*)carve(786432ull * 2);
    unsigned short* meanb  = (unsigned short*)carve(81920ull * 2);
    unsigned short* att1b  = (unsigned short*)carve(1605632ull * 2);
    unsigned short* Hallb  = (unsigned short*)carve(1572864ull * 2);
    unsigned short* zb     = (unsigned short*)carve(180224ull * 2);
    float* bz   = (float*)carve(4096ull * 4);
    float* att2 = (float*)carve(32768ull * 4);
    float* cst  = (float*)carve(65536ull * 4);

    uber_init<<<118992, 256, 0, stream>>>(Wih, Whh, bih, bhh, WoutF, Weatt, Wdatt,
        Wh0, Wc0, enc, caps, embed, Wzb, Woutb, Weattb, Wdattb, Wh0b, Wc0b,
        encb, embb, meanb, bz);

    // h0 -> bf16 into z h-slot (ldc 2816); c0 -> fp32 c_state
    gemm64_bn16<1><<<64, 256, 0, stream>>>(meanb, 1280, Wh0b, 1280, bh0, zb + 1792, 2816);
    gemm64_bn16<0><<<64, 256, 0, stream>>>(meanb, 1280, Wc0b, 1280, bc0, cst, 1024);

    // att1 = enc @ W_eatt^T + b_eatt  (bf16 out)
    gemm_att1_k<<<dim3(8, 49), 256, 0, stream>>>(encb, Weattb, beatt, att1b);

    for (int t = 0; t < 24; ++t) {
        gemm64_bn16<0><<<32, 256, 0, stream>>>(zb + 1792, 2816, Wdattb, 1024, bdatt, att2, 512);
        attn_ctx_k<<<64, 256, 0, stream>>>(att2, att1b, Wfatt, bfatt, encb, embb, zb, t);
        gates_lstm_k<<<256, 256, 0, stream>>>(zb, Wzb, bz, cst, zb + 1792,
                                              Hallb + (size_t)t * 64 * 1024);
    }

    preds_k<<<dim3(79, 12), 256, 0, stream>>>(Hallb, Woutb, bout, out);
}

// Round 2
// 1136.816 us; speedup vs baseline: 1.0186x; 1.0186x over previous
//
#include <hip/hip_runtime.h>
#include <hip/hip_bf16.h>

typedef float  v4f __attribute__((ext_vector_type(4)));
typedef short  v8s __attribute__((ext_vector_type(8)));
typedef int    v4i __attribute__((ext_vector_type(4)));

#define DEV static __device__ __forceinline__

DEV float bf2f(unsigned short u) {
    union { unsigned int i; float f; } x; x.i = ((unsigned int)u) << 16; return x.f;
}
DEV unsigned short f2bf(float f) {
    union { float f; unsigned int i; } x; x.f = f;
    unsigned int r = x.i + 0x7fff + ((x.i >> 16) & 1);
    return (unsigned short)(r >> 16);
}
DEV float sigm(float x) { return 1.f / (1.f + __expf(-x)); }

DEV v4i pack8(const float* f) {
    v4i o;
#pragma unroll
    for (int q = 0; q < 4; ++q)
        ((unsigned int*)&o)[q] = (unsigned int)f2bf(f[2 * q]) |
                                 ((unsigned int)f2bf(f[2 * q + 1]) << 16);
    return o;
}
DEV float lo16(unsigned int x) { union { unsigned int i; float f; } u; u.i = x << 16; return u.f; }
DEV float hi16(unsigned int x) { union { unsigned int i; float f; } u; u.i = x & 0xffff0000u; return u.f; }

// ---------------------------------------------------------------------------
// uber_init: 8 elements per thread, 16B loads + 16B stores.
// ---------------------------------------------------------------------------
__global__ __launch_bounds__(256) void uber_init(
    const float* __restrict__ Wih, const float* __restrict__ Whh,
    const float* __restrict__ bih, const float* __restrict__ bhh,
    const float* __restrict__ WoutF, const float* __restrict__ WeattF,
    const float* __restrict__ WdattF, const float* __restrict__ Wh0F,
    const float* __restrict__ Wc0F, const float* __restrict__ enc,
    const int* __restrict__ caps, const float* __restrict__ embed,
    unsigned short* __restrict__ Wz, unsigned short* __restrict__ Woutb,
    unsigned short* __restrict__ Weattb, unsigned short* __restrict__ Wdattb,
    unsigned short* __restrict__ Wh0b, unsigned short* __restrict__ Wc0b,
    unsigned short* __restrict__ encb, unsigned short* __restrict__ embb,
    unsigned short* __restrict__ meanb, float* __restrict__ bz)
{
    const int i = (blockIdx.x * 256 + threadIdx.x) * 8;
    float f[8];
    if (i < 11534336) {                       // Wz = [W_ih | W_hh] rows of 2816
        int n = i / 2816, k = i - n * 2816;
        const float* src = (k < 1792) ? &Wih[n * 1792 + k] : &Whh[n * 1024 + (k - 1792)];
        *(v4f*)&f[0] = *(const v4f*)src; *(v4f*)&f[4] = *(const v4f*)(src + 4);
        *(v4i*)&Wz[i] = pack8(f);
    } else if (i < 21774336) {                // W_out
        int j = i - 11534336;
        *(v4f*)&f[0] = *(const v4f*)&WoutF[j]; *(v4f*)&f[4] = *(const v4f*)&WoutF[j + 4];
        *(v4i*)&Woutb[j] = pack8(f);
    } else if (i < 22429696) {                // W_eatt
        int j = i - 21774336;
        *(v4f*)&f[0] = *(const v4f*)&WeattF[j]; *(v4f*)&f[4] = *(const v4f*)&WeattF[j + 4];
        *(v4i*)&Weattb[j] = pack8(f);
    } else if (i < 22953984) {                // W_datt
        int j = i - 22429696;
        *(v4f*)&f[0] = *(const v4f*)&WdattF[j]; *(v4f*)&f[4] = *(const v4f*)&WdattF[j + 4];
        *(v4i*)&Wdattb[j] = pack8(f);
    } else if (i < 24264704) {                // W_h0
        int j = i - 22953984;
        *(v4f*)&f[0] = *(const v4f*)&Wh0F[j]; *(v4f*)&f[4] = *(const v4f*)&Wh0F[j + 4];
        *(v4i*)&Wh0b[j] = pack8(f);
    } else if (i < 25575424) {                // W_c0
        int j = i - 24264704;
        *(v4f*)&f[0] = *(const v4f*)&Wc0F[j]; *(v4f*)&f[4] = *(const v4f*)&Wc0F[j + 4];
        *(v4i*)&Wc0b[j] = pack8(f);
    } else if (i < 29589504) {                // encoder_out
        int j = i - 25575424;
        *(v4f*)&f[0] = *(const v4f*)&enc[j]; *(v4f*)&f[4] = *(const v4f*)&enc[j + 4];
        *(v4i*)&encb[j] = pack8(f);
    } else if (i < 30375936) {                // emb gather (t < 24 only)
        int j = i - 29589504;
        int b = j / 12288, r = j - b * 12288, t = r / 512, e = r - t * 512;
        const float* src = &embed[caps[b * 25 + t] * 512 + e];
        *(v4f*)&f[0] = *(const v4f*)src; *(v4f*)&f[4] = *(const v4f*)(src + 4);
        *(v4i*)&embb[j] = pack8(f);
    } else if (i < 30457856) {                // mean over P=49
        int j = i - 30375936;
        int b = j / 1280, c = j - b * 1280;
#pragma unroll
        for (int q = 0; q < 8; ++q) f[q] = 0.f;
        for (int p = 0; p < 49; ++p) {
            const float* src = &enc[(b * 49 + p) * 1280 + c];
            v4f a = *(const v4f*)src, bq = *(const v4f*)(src + 4);
#pragma unroll
            for (int q = 0; q < 4; ++q) { f[q] += a[q]; f[q + 4] += bq[q]; }
        }
#pragma unroll
        for (int q = 0; q < 8; ++q) f[q] *= (1.f / 49.f);
        *(v4i*)&meanb[j] = pack8(f);
    } else if (i < 30461952) {                // bz = b_ih + b_hh
        int j = i - 30457856;
#pragma unroll
        for (int q = 0; q < 8; ++q) f[q] = bih[j + q] + bhh[j + q];
        *(v4f*)&bz[j] = *(v4f*)&f[0]; *(v4f*)&bz[j + 4] = *(v4f*)&f[4];
    }
}

// ---------------------------------------------------------------------------
// gemm64_bn16: C[64,N] = A[64,K](bf16) @ B[N,K](bf16)^T + bias. BN=16/block.
// Register-double-buffered staging.
// ---------------------------------------------------------------------------
template <int OUT_BF16>
__global__ __launch_bounds__(256) void gemm64_bn16(
    const unsigned short* __restrict__ Ag, int lda,
    const unsigned short* __restrict__ Bg, int K,
    const float* __restrict__ bias, void* __restrict__ Cg, int ldc)
{
    __shared__ unsigned short lA[64 * 264];
    __shared__ unsigned short lB[16 * 264];
    const int tid = threadIdx.x, lane = tid & 63, w = tid >> 6;
    const int nb = blockIdx.x * 16;
    const int rA = tid >> 5, cA = (tid & 31) * 8;
    v4f acc = {0.f, 0.f, 0.f, 0.f};
    v4i ra[8], rb[2];
#pragma unroll
    for (int i = 0; i < 8; ++i)
        ra[i] = *(const v4i*)&Ag[(rA + i * 8) * lda + cA];
#pragma unroll
    for (int i = 0; i < 2; ++i)
        rb[i] = *(const v4i*)&Bg[(nb + rA + i * 8) * K + cA];
    for (int kt = 0; kt < K; kt += 256) {
#pragma unroll
        for (int i = 0; i < 8; ++i) *(v4i*)&lA[(rA + i * 8) * 264 + cA] = ra[i];
#pragma unroll
        for (int i = 0; i < 2; ++i) *(v4i*)&lB[(rA + i * 8) * 264 + cA] = rb[i];
        __syncthreads();
        if (kt + 256 < K) {
#pragma unroll
            for (int i = 0; i < 8; ++i)
                ra[i] = *(const v4i*)&Ag[(rA + i * 8) * lda + kt + 256 + cA];
#pragma unroll
            for (int i = 0; i < 2; ++i)
                rb[i] = *(const v4i*)&Bg[(nb + rA + i * 8) * K + kt + 256 + cA];
        }
#pragma unroll
        for (int ks = 0; ks < 8; ++ks) {
            v8s a = *(const v8s*)&lA[(w * 16 + (lane & 15)) * 264 + ks * 32 + (lane >> 4) * 8];
            v8s b = *(const v8s*)&lB[(lane & 15) * 264 + ks * 32 + (lane >> 4) * 8];
            acc = __builtin_amdgcn_mfma_f32_16x16x32_bf16(a, b, acc, 0, 0, 0);
        }
        __syncthreads();
    }
    const int n = nb + (lane & 15);
    const float bs = bias[n];
#pragma unroll
    for (int r = 0; r < 4; ++r) {
        int m = w * 16 + (lane >> 4) * 4 + r;
        float v = acc[r] + bs;
        if (OUT_BF16) ((unsigned short*)Cg)[m * ldc + n] = f2bf(v);
        else          ((float*)Cg)[m * ldc + n] = v;
    }
}

// ---------------------------------------------------------------------------
// gemm_att1: att1[3136,512](bf16) = enc_b[3136,1280] @ W_eatt[512,1280]^T + b
// Tile 64x64, BK=128, reg-dbuf. grid = (8, 49)
// ---------------------------------------------------------------------------
__global__ __launch_bounds__(256) void gemm_att1_k(
    const unsigned short* __restrict__ Aenc, const unsigned short* __restrict__ Bw,
    const float* __restrict__ bias, unsigned short* __restrict__ Cout)
{
    __shared__ unsigned short lA[64 * 136];
    __shared__ unsigned short lB[64 * 136];
    const int tid = threadIdx.x, lane = tid & 63, w = tid >> 6;
    const int mb = blockIdx.y * 64, nb = blockIdx.x * 64;
    const int rT = tid >> 4, cT = (tid & 15) * 8;
    v4f acc[4];
#pragma unroll
    for (int f = 0; f < 4; ++f) acc[f] = (v4f){0.f, 0.f, 0.f, 0.f};
    v4i ra[4], rb[4];
#pragma unroll
    for (int i = 0; i < 4; ++i) {
        ra[i] = *(const v4i*)&Aenc[(mb + rT + i * 16) * 1280 + cT];
        rb[i] = *(const v4i*)&Bw[(nb + rT + i * 16) * 1280 + cT];
    }
    for (int kt = 0; kt < 1280; kt += 128) {
#pragma unroll
        for (int i = 0; i < 4; ++i) {
            *(v4i*)&lA[(rT + i * 16) * 136 + cT] = ra[i];
            *(v4i*)&lB[(rT + i * 16) * 136 + cT] = rb[i];
        }
        __syncthreads();
        if (kt + 128 < 1280) {
#pragma unroll
            for (int i = 0; i < 4; ++i) {
                ra[i] = *(const v4i*)&Aenc[(mb + rT + i * 16) * 1280 + kt + 128 + cT];
                rb[i] = *(const v4i*)&Bw[(nb + rT + i * 16) * 1280 + kt + 128 + cT];
            }
        }
#pragma unroll
        for (int ks = 0; ks < 4; ++ks) {
            v8s a = *(const v8s*)&lA[(w * 16 + (lane & 15)) * 136 + ks * 32 + (lane >> 4) * 8];
#pragma unroll
            for (int f = 0; f < 4; ++f) {
                v8s b = *(const v8s*)&lB[(f * 16 + (lane & 15)) * 136 + ks * 32 + (lane >> 4) * 8];
                acc[f] = __builtin_amdgcn_mfma_f32_16x16x32_bf16(a, b, acc[f], 0, 0, 0);
            }
        }
        __syncthreads();
    }
#pragma unroll
    for (int f = 0; f < 4; ++f) {
        int n = nb + f * 16 + (lane & 15);
        float bs = bias[n];
#pragma unroll
        for (int r = 0; r < 4; ++r) {
            int m = mb + w * 16 + (lane >> 4) * 4 + r;
            Cout[m * 512 + n] = f2bf(acc[f][r] + bs);
        }
    }
}

// ---------------------------------------------------------------------------
// attn_ctx: per-b block. Vectorized v4i loads of att1 rows + enc rows.
// ---------------------------------------------------------------------------
__global__ __launch_bounds__(256) void attn_ctx_k(
    const float* __restrict__ att2, const unsigned short* __restrict__ att1b,
    const float* __restrict__ Wfatt, const float* __restrict__ bfatt,
    const unsigned short* __restrict__ encb, const unsigned short* __restrict__ embb,
    unsigned short* __restrict__ z, int tstep)
{
    __shared__ float a2[512];
    __shared__ float wf[512];
    __shared__ float es[64];
    __shared__ float alpha[64];
    const int tid = threadIdx.x, lane = tid & 63, w = tid >> 6;
    const int b = blockIdx.x;
    a2[tid]       = att2[b * 512 + tid];
    a2[tid + 256] = att2[b * 512 + tid + 256];
    wf[tid]       = Wfatt[tid];
    wf[tid + 256] = Wfatt[tid + 256];
    __syncthreads();
    // scores: one att1 row per wave-iteration, lane reads 8 contiguous bf16
    for (int p = w; p < 49; p += 4) {
        v4i u = *(const v4i*)&att1b[(b * 49 + p) * 512 + lane * 8];
        v4f c0 = *(const v4f*)&a2[lane * 8], c1 = *(const v4f*)&a2[lane * 8 + 4];
        v4f w0 = *(const v4f*)&wf[lane * 8], w1 = *(const v4f*)&wf[lane * 8 + 4];
        float s = 0.f;
#pragma unroll
        for (int q = 0; q < 4; ++q) {
            unsigned int x = ((unsigned int*)&u)[q];
            float vlo = lo16(x), vhi = hi16(x);
            float clo = (q < 2) ? c0[q * 2] : c1[q * 2 - 4];
            float chi = (q < 2) ? c0[q * 2 + 1] : c1[q * 2 - 3];
            float wlo = (q < 2) ? w0[q * 2] : w1[q * 2 - 4];
            float whi = (q < 2) ? w0[q * 2 + 1] : w1[q * 2 - 3];
            s += fmaxf(vlo + clo, 0.f) * wlo;
            s += fmaxf(vhi + chi, 0.f) * whi;
        }
#pragma unroll
        for (int off = 32; off > 0; off >>= 1) s += __shfl_xor(s, off);
        if (lane == 0) es[p] = s + bfatt[0];
    }
    __syncthreads();
    if (w == 0) {
        float v = (lane < 49) ? es[lane] : -1e30f;
        float m = v;
#pragma unroll
        for (int off = 32; off > 0; off >>= 1) m = fmaxf(m, __shfl_xor(m, off));
        float e = (lane < 49) ? __expf(v - m) : 0.f;
        float s = e;
#pragma unroll
        for (int off = 32; off > 0; off >>= 1) s += __shfl_xor(s, off);
        if (lane < 49) alpha[lane] = e / s;
    }
    __syncthreads();
    // ctx: 160 threads x 8 consecutive columns, v4i row loads
    if (tid < 160) {
        const int jb = tid * 8;
        float acc[8];
#pragma unroll
        for (int q = 0; q < 8; ++q) acc[q] = 0.f;
        for (int p = 0; p < 49; ++p) {
            v4i u = *(const v4i*)&encb[(b * 49 + p) * 1280 + jb];
            float al = alpha[p];
#pragma unroll
            for (int q = 0; q < 4; ++q) {
                unsigned int x = ((unsigned int*)&u)[q];
                acc[2 * q]     += al * lo16(x);
                acc[2 * q + 1] += al * hi16(x);
            }
        }
        *(v4i*)&z[b * 2816 + 512 + jb] = pack8(acc);
    }
    // emb copy: 64 threads x 8 shorts
    if (tid < 64)
        *(v4i*)&z[b * 2816 + tid * 8] = *(const v4i*)&embb[(b * 24 + tstep) * 512 + tid * 8];
}

// ---------------------------------------------------------------------------
// gates_lstm: gates[64,4096] = z[64,2816] @ Wz^T + bz, fused LSTM epilogue.
// Reg-dbuf staging. grid = 256 (block owns 4 h-cols x 4 gates).
// ---------------------------------------------------------------------------
__global__ __launch_bounds__(256) void gates_lstm_k(
    const unsigned short* __restrict__ z, const unsigned short* __restrict__ Wz,
    const float* __restrict__ bz, float* __restrict__ cst,
    unsigned short* __restrict__ zh, unsigned short* __restrict__ HallT)
{
    __shared__ unsigned short lA[64 * 264];
    __shared__ unsigned short lB[16 * 264];
    __shared__ float gbuf[64 * 20];
    const int tid = threadIdx.x, lane = tid & 63, w = tid >> 6;
    const int hb = blockIdx.x * 4;
    const int rT = tid >> 5, cT = (tid & 31) * 8;
    const int gate = rT & 3, hco = rT >> 2;
    const int growB = (gate * 1024 + hb + hco) * 2816;       // lB row rT
    const int growB2 = (((rT + 8) & 3) * 1024 + hb + ((rT + 8) >> 2)) * 2816;
    v4f acc = {0.f, 0.f, 0.f, 0.f};
    v4i ra[8], rb[2];
#pragma unroll
    for (int i = 0; i < 8; ++i)
        ra[i] = *(const v4i*)&z[(rT + i * 8) * 2816 + cT];
    rb[0] = *(const v4i*)&Wz[growB + cT];
    rb[1] = *(const v4i*)&Wz[growB2 + cT];
    for (int kt = 0; kt < 2816; kt += 256) {
#pragma unroll
        for (int i = 0; i < 8; ++i) *(v4i*)&lA[(rT + i * 8) * 264 + cT] = ra[i];
        *(v4i*)&lB[rT * 264 + cT] = rb[0];
        *(v4i*)&lB[(rT + 8) * 264 + cT] = rb[1];
        __syncthreads();
        if (kt + 256 < 2816) {
#pragma unroll
            for (int i = 0; i < 8; ++i)
                ra[i] = *(const v4i*)&z[(rT + i * 8) * 2816 + kt + 256 + cT];
            rb[0] = *(const v4i*)&Wz[growB + kt + 256 + cT];
            rb[1] = *(const v4i*)&Wz[growB2 + kt + 256 + cT];
        }
#pragma unroll
        for (int ks = 0; ks < 8; ++ks) {
            v8s a = *(const v8s*)&lA[(w * 16 + (lane & 15)) * 264 + ks * 32 + (lane >> 4) * 8];
            v8s b = *(const v8s*)&lB[(lane & 15) * 264 + ks * 32 + (lane >> 4) * 8];
            acc = __builtin_amdgcn_mfma_f32_16x16x32_bf16(a, b, acc, 0, 0, 0);
        }
        __syncthreads();
    }
#pragma unroll
    for (int r = 0; r < 4; ++r) {
        int m = w * 16 + (lane >> 4) * 4 + r;   // = b
        int n = lane & 15;                      // = hco*4 + gate
        gbuf[m * 20 + n] = acc[r];
    }
    __syncthreads();
    const int b = tid >> 2, hc2 = tid & 3, hidx = hb + hc2;
    float gi = gbuf[b * 20 + hc2 * 4 + 0] + bz[hidx];
    float gf = gbuf[b * 20 + hc2 * 4 + 1] + bz[1024 + hidx];
    float gg = gbuf[b * 20 + hc2 * 4 + 2] + bz[2048 + hidx];
    float go = gbuf[b * 20 + hc2 * 4 + 3] + bz[3072 + hidx];
    float cn = sigm(gf) * cst[b * 1024 + hidx] + sigm(gi) * tanhf(gg);
    float hn = sigm(go) * tanhf(cn);
    cst[b * 1024 + hidx] = cn;
    unsigned short hb16 = f2bf(hn);
    zh[b * 2816 + hidx] = hb16;
    HallT[b * 1024 + hidx] = hb16;
}

// ---------------------------------------------------------------------------
// preds: out = Hall[1536,1024] @ W_out[10000,1024]^T + b_out
// Tile 128x128, BK=64, reg-dbuf. grid = (79, 12).
// ---------------------------------------------------------------------------
__global__ __launch_bounds__(256) void preds_k(
    const unsigned short* __restrict__ Hall, const unsigned short* __restrict__ Wout,
    const float* __restrict__ bout, float* __restrict__ out)
{
    __shared__ unsigned short lA[128 * 72];
    __shared__ unsigned short lB[128 * 72];
    const int tid = threadIdx.x, lane = tid & 63, w = tid >> 6;
    const int mb = blockIdx.y * 128, nb = blockIdx.x * 128;
    const int rT = tid >> 3, cT = (tid & 7) * 8;
    int nB = nb + rT; if (nB > 9999) nB = 9999;
    v4f acc[2][8];
#pragma unroll
    for (int i = 0; i < 2; ++i)
#pragma unroll
        for (int f = 0; f < 8; ++f) acc[i][f] = (v4f){0.f, 0.f, 0.f, 0.f};
    v4i ra[4], rb[4];
#pragma unroll
    for (int i = 0; i < 4; ++i) {
        ra[i] = *(const v4i*)&Hall[(mb + rT + i * 32) * 1024 + cT];
        int n2 = nb + rT + i * 32; if (n2 > 9999) n2 = 9999;
        rb[i] = *(const v4i*)&Wout[n2 * 1024 + cT];
    }
    for (int kt = 0; kt < 1024; kt += 64) {
#pragma unroll
        for (int i = 0; i < 4; ++i) {
            *(v4i*)&lA[(rT + i * 32) * 72 + cT] = ra[i];
            *(v4i*)&lB[(rT + i * 32) * 72 + cT] = rb[i];
        }
        __syncthreads();
        if (kt + 64 < 1024) {
#pragma unroll
            for (int i = 0; i < 4; ++i) {
                ra[i] = *(const v4i*)&Hall[(mb + rT + i * 32) * 1024 + kt + 64 + cT];
                int n2 = nb + rT + i * 32; if (n2 > 9999) n2 = 9999;
                rb[i] = *(const v4i*)&Wout[n2 * 1024 + kt + 64 + cT];
            }
        }
#pragma unroll
        for (int ks = 0; ks < 2; ++ks) {
            int ko = ks * 32 + (lane >> 4) * 8;
            v8s a0 = *(const v8s*)&lA[(w * 32 + (lane & 15)) * 72 + ko];
            v8s a1 = *(const v8s*)&lA[(w * 32 + 16 + (lane & 15)) * 72 + ko];
#pragma unroll
            for (int f = 0; f < 8; ++f) {
                v8s b = *(const v8s*)&lB[(f * 16 + (lane & 15)) * 72 + ko];
                acc[0][f] = __builtin_amdgcn_mfma_f32_16x16x32_bf16(a0, b, acc[0][f], 0, 0, 0);
                acc[1][f] = __builtin_amdgcn_mfma_f32_16x16x32_bf16(a1, b, acc[1][f], 0, 0, 0);
            }
        }
        __syncthreads();
    }
#pragma unroll
    for (int f = 0; f < 8; ++f) {
        int n = nb + f * 16 + (lane & 15);
        if (n < 10000) {
            float bs = bout[n];
#pragma unroll
            for (int i = 0; i < 2; ++i)
#pragma unroll
                for (int r = 0; r < 4; ++r) {
                    int m = mb + w * 32 + i * 16 + (lane >> 4) * 4 + r;
                    int tt = m >> 6, bb = m & 63;
                    out[(bb * 24 + tt) * 10000 + n] = acc[i][f][r] + bs;
                }
        }
    }
}

// ---------------------------------------------------------------------------
extern "C" void kernel_launch(void* const* d_in, const int* in_sizes, int n_in,
                              void* d_out, int out_size, void* d_ws, size_t ws_size,
                              hipStream_t stream)
{
    const float* enc   = (const float*)d_in[0];
    const int*   caps  = (const int*)d_in[1];
    const float* embed = (const float*)d_in[2];
    const float* Weatt = (const float*)d_in[3];
    const float* beatt = (const float*)d_in[4];
    const float* Wdatt = (const float*)d_in[5];
    const float* bdatt = (const float*)d_in[6];
    const float* Wfatt = (const float*)d_in[7];
    const float* bfatt = (const float*)d_in[8];
    const float* Wih   = (const float*)d_in[9];
    const float* bih   = (const float*)d_in[10];
    const float* Whh   = (const float*)d_in[11];
    const float* bhh   = (const float*)d_in[12];
    const float* Wh0   = (const float*)d_in[13];
    const float* bh0   = (const float*)d_in[14];
    const float* Wc0   = (const float*)d_in[15];
    const float* bc0   = (const float*)d_in[16];
    const float* WoutF = (const float*)d_in[17];
    const float* bout  = (const float*)d_in[18];
    float* out = (float*)d_out;

    char* ws = (char*)d_ws;
    size_t off = 0;
    auto carve = [&](size_t bytes) -> void* {
        void* p = ws + off; off += (bytes + 255) & ~(size_t)255; return p;
    };
    unsigned short* Wzb    = (unsigned short*)carve(11534336ull * 2);
    unsigned short* Woutb  = (unsigned short*)carve(10240000ull * 2);
    unsigned short* Weattb = (unsigned short*)carve(655360ull * 2);
    unsigned short* Wdattb = (unsigned short*)carve(524288ull * 2);
    unsigned short* Wh0b   = (unsigned short*)carve(1310720ull * 2);
    unsigned short* Wc0b   = (unsigned short*)carve(1310720ull * 2);
    unsigned short* encb   = (unsigned short*)carve(4014080ull * 2);
    unsigned short* embb   = (unsigned short*)carve(786432ull * 2);
    unsigned short* meanb  = (unsigned short*)carve(81920ull * 2);
    unsigned short* att1b  = (unsigned short*)carve(1605632ull * 2);
    unsigned short* Hallb  = (unsigned short*)carve(1572864ull * 2);
    unsigned short* zb     = (unsigned short*)carve(180224ull * 2);
    float* bz   = (float*)carve(4096ull * 4);
    float* att2 = (float*)carve(32768ull * 4);
    float* cst  = (float*)carve(65536ull * 4);

    uber_init<<<14874, 256, 0, stream>>>(Wih, Whh, bih, bhh, WoutF, Weatt, Wdatt,
        Wh0, Wc0, enc, caps, embed, Wzb, Woutb, Weattb, Wdattb, Wh0b, Wc0b,
        encb, embb, meanb, bz);

    gemm64_bn16<1><<<64, 256, 0, stream>>>(meanb, 1280, Wh0b, 1280, bh0, zb + 1792, 2816);
    gemm64_bn16<0><<<64, 256, 0, stream>>>(meanb, 1280, Wc0b, 1280, bc0, cst, 1024);

    gemm_att1_k<<<dim3(8, 49), 256, 0, stream>>>(encb, Weattb, beatt, att1b);

    for (int t = 0; t < 24; ++t) {
        gemm64_bn16<0><<<32, 256, 0, stream>>>(zb + 1792, 2816, Wdattb, 1024, bdatt, att2, 512);
        attn_ctx_k<<<64, 256, 0, stream>>>(att2, att1b, Wfatt, bfatt, encb, embb, zb, t);
        gates_lstm_k<<<256, 256, 0, stream>>>(zb, Wzb, bz, cst, zb + 1792,
                                              Hallb + (size_t)t * 64 * 1024);
    }

    preds_k<<<dim3(79, 12), 256, 0, stream>>>(Hallb, Woutb, bout, out);
}